// Round 4
// baseline (235.400 us; speedup 1.0000x reference)
//
#include <hip/hip_runtime.h>

#define LAMBDA_COORD 5.0f
#define LAMBDA_NOOBJ 0.5f

// 802816 cells; preds 30 f32/cell (120 B), targets 25 f32/cell (100 B).
// Each lane loads its whole cell with dword-aligned wide loads (gfx950
// global_load_dwordx4 needs only 4 B alignment). Values live in NAMED
// ext-vector variables -> SROA-proof, zero scratch.
// R4: 512-thr blocks (4 blocks/CU = 32 waves = HW cap), launch_bounds(512,8)
// caps VGPR at 64 (2x the R3 budget -> more loads in flight), nontemporal
// loads (zero-reuse streaming).

typedef float f4u __attribute__((ext_vector_type(4), aligned(4)));
typedef float f2u __attribute__((ext_vector_type(2), aligned(4)));

__global__ void zero_out_kernel(float* out, int n) {
    int i = blockIdx.x * blockDim.x + threadIdx.x;
    if (i < n) out[i] = 0.0f;
}

__global__ __launch_bounds__(512, 8) void yolo_loss_kernel(
    const float* __restrict__ preds, const float* __restrict__ targets,
    float* __restrict__ out, int n_cells)
{
    __shared__ float s_part[8];
    const int tid = threadIdx.x;
    const int c = blockIdx.x * 512 + tid;

    float loss = 0.0f;
    if (c < n_cells) {
        const float* pbase = preds + (size_t)c * 30;
        const float* tbase = targets + (size_t)c * 25;
        const f4u* pp = (const f4u*)pbase;
        const f4u* tp = (const f4u*)tbase;

        // preds p[0..29] — all loads issued before any use
        f4u P0 = __builtin_nontemporal_load(pp + 0);
        f4u P1 = __builtin_nontemporal_load(pp + 1);
        f4u P2 = __builtin_nontemporal_load(pp + 2);
        f4u P3 = __builtin_nontemporal_load(pp + 3);
        f4u P4 = __builtin_nontemporal_load(pp + 4);
        f4u P5 = __builtin_nontemporal_load(pp + 5);
        f4u P6 = __builtin_nontemporal_load(pp + 6);
        f2u P7 = __builtin_nontemporal_load((const f2u*)(pbase + 28));
        // targets t[0..24]
        f4u T0 = __builtin_nontemporal_load(tp + 0);
        f4u T1 = __builtin_nontemporal_load(tp + 1);
        f4u T2 = __builtin_nontemporal_load(tp + 2);
        f4u T3 = __builtin_nontemporal_load(tp + 3);
        f4u T4 = __builtin_nontemporal_load(tp + 4);
        f4u T5 = __builtin_nontemporal_load(tp + 5);
        float t24 = __builtin_nontemporal_load(tbase + 24);

        // box confidences: p[0], p[5]
        float p0 = P0.x, p5c = P1.y;
        // jnp.argmax picks first index on tie -> box1 only on strict greater.
        bool pick1 = p5c > p0;
        float b0 = pick1 ? p5c  : p0;
        float b1 = pick1 ? P1.z : P0.y;   // p[6] : p[1]
        float b2 = pick1 ? P1.w : P0.z;   // p[7] : p[2]
        float b3 = pick1 ? P2.x : P0.w;   // p[8] : p[3]
        float b4 = pick1 ? P2.y : P1.x;   // p[9] : p[4]

        float t0 = T0.x;
        float d1 = b1 - T0.y, d2 = b2 - T0.z, d3 = b3 - T0.w, d4 = b4 - T1.x;
        float box_loss = d1 * d1 + d2 * d2 + d3 * d3 + d4 * d4;
        float dpc = b0 - t0;
        float pc_loss = dpc * dpc;

        // classes: p[10..29] vs t[5..24]
        float cl = 0.0f, d;
        d = P2.z - T1.y; cl += d * d;
        d = P2.w - T1.z; cl += d * d;
        d = P3.x - T1.w; cl += d * d;
        d = P3.y - T2.x; cl += d * d;
        d = P3.z - T2.y; cl += d * d;
        d = P3.w - T2.z; cl += d * d;
        d = P4.x - T2.w; cl += d * d;
        d = P4.y - T3.x; cl += d * d;
        d = P4.z - T3.y; cl += d * d;
        d = P4.w - T3.z; cl += d * d;
        d = P5.x - T3.w; cl += d * d;
        d = P5.y - T4.x; cl += d * d;
        d = P5.z - T4.y; cl += d * d;
        d = P5.w - T4.z; cl += d * d;
        d = P6.x - T4.w; cl += d * d;
        d = P6.y - T5.x; cl += d * d;
        d = P6.z - T5.y; cl += d * d;
        d = P6.w - T5.z; cl += d * d;
        d = P7.x - T5.w; cl += d * d;
        d = P7.y - t24;  cl += d * d;

        float obj_term = LAMBDA_COORD * box_loss + pc_loss + cl;
        float noobj_term = LAMBDA_NOOBJ * (p0 * p0 + p5c * p5c);
        loss = (t0 == 1.0f) ? obj_term : noobj_term;
    }

    // wave (64-lane) shuffle reduction
    #pragma unroll
    for (int off = 32; off > 0; off >>= 1)
        loss += __shfl_down(loss, off, 64);

    const int wave = tid >> 6;
    if ((tid & 63) == 0) s_part[wave] = loss;
    __syncthreads();
    if (tid == 0) {
        float s = 0.0f;
        #pragma unroll
        for (int w = 0; w < 8; ++w) s += s_part[w];
        atomicAdd(out, s);
    }
}

extern "C" void kernel_launch(void* const* d_in, const int* in_sizes, int n_in,
                              void* d_out, int out_size, void* d_ws, size_t ws_size,
                              hipStream_t stream) {
    const float* preds   = (const float*)d_in[0];
    const float* targets = (const float*)d_in[1];
    float* out = (float*)d_out;

    const int n_cells = in_sizes[0] / 30;   // 802816 = 1568 * 512

    // d_out is poisoned (0xAA) before every timed replay — zero it on-stream.
    zero_out_kernel<<<(out_size + 255) / 256, 256, 0, stream>>>(out, out_size);

    const int grid = (n_cells + 511) / 512; // 1568
    yolo_loss_kernel<<<grid, 512, 0, stream>>>(preds, targets, out, n_cells);
}

// Round 5
// 195.744 us; speedup vs baseline: 1.2026x; 1.2026x over previous
//
#include <hip/hip_runtime.h>
#include <stdint.h>

#define LAMBDA_COORD 5.0f
#define LAMBDA_NOOBJ 0.5f

// 802816 cells; preds 30 f32/cell, targets 25 f32/cell.
// R5: per-WAVE 64-cell tiles staged into wave-private LDS slices with
// global_load_lds width=16 (perfectly coalesced: 16 lines/instr vs ~60 for
// the per-lane-cell pattern that capped R3 at L1 address processing).
// No __syncthreads in the loop — only wave-local s_waitcnt. 64 cells =
// 480 pred f4 (7.5/lane) + 400 targ f4 (6.25/lane), staged as 7+partial
// and 6+partial exec-guarded load instructions.

__global__ void zero_out_kernel(float* out, int n) {
    int i = blockIdx.x * blockDim.x + threadIdx.x;
    if (i < n) out[i] = 0.0f;
}

__global__ __launch_bounds__(256) void yolo_loss_kernel(
    const float* __restrict__ preds, const float* __restrict__ targets,
    float* __restrict__ out, int n_cells)
{
    // per wave: 1920 pred floats + 1600 targ floats = 3520 floats (14080 B)
    __shared__ float lds[4 * 3520];
    __shared__ float s_part[4];

    const int tid  = threadIdx.x;
    const int lane = tid & 63;
    const int wv   = tid >> 6;
    float* const pbase = lds + wv * 3520;        // 14080-B slice, 16B-aligned
    float* const tbase = pbase + 1920;

    const int ntiles = n_cells >> 6;             // 12544 (n_cells % 64 == 0)
    const int gwave  = (blockIdx.x * 256 + tid) >> 6;
    const int nwaves = gridDim.x * 4;

    float loss = 0.0f;
    for (int tile = gwave; tile < ntiles; tile += nwaves) {
        const float4* pg = (const float4*)preds   + (size_t)tile * 480;
        const float4* tg = (const float4*)targets + (size_t)tile * 400;

        // ---- stage preds: 480 f4 = 7 full + 32-lane partial ----
        #pragma unroll
        for (int r = 0; r < 7; ++r)
            __builtin_amdgcn_global_load_lds(
                (const __attribute__((address_space(1))) void*)(pg + r * 64 + lane),
                (__attribute__((address_space(3))) void*)(pbase + r * 256), 16, 0, 0);
        if (lane < 32)
            __builtin_amdgcn_global_load_lds(
                (const __attribute__((address_space(1))) void*)(pg + 448 + lane),
                (__attribute__((address_space(3))) void*)(pbase + 1792), 16, 0, 0);
        // ---- stage targets: 400 f4 = 6 full + 16-lane partial ----
        #pragma unroll
        for (int r = 0; r < 6; ++r)
            __builtin_amdgcn_global_load_lds(
                (const __attribute__((address_space(1))) void*)(tg + r * 64 + lane),
                (__attribute__((address_space(3))) void*)(tbase + r * 256), 16, 0, 0);
        if (lane < 16)
            __builtin_amdgcn_global_load_lds(
                (const __attribute__((address_space(1))) void*)(tg + 384 + lane),
                (__attribute__((address_space(3))) void*)(tbase + 1536), 16, 0, 0);

        // wave-local wait for LDS arrival (no block barrier anywhere)
        asm volatile("s_waitcnt vmcnt(0)" ::: "memory");

        const float* p = pbase + 30 * lane;
        const float* t = tbase + 25 * lane;

        float p0 = p[0], p5 = p[5];
        // jnp.argmax picks first index on tie -> box1 only on strict greater.
        bool pick1 = p5 > p0;
        float b0 = pick1 ? p5   : p0;
        float b1 = pick1 ? p[6] : p[1];
        float b2 = pick1 ? p[7] : p[2];
        float b3 = pick1 ? p[8] : p[3];
        float b4 = pick1 ? p[9] : p[4];

        float t0 = t[0];
        float d1 = b1 - t[1], d2 = b2 - t[2], d3 = b3 - t[3], d4 = b4 - t[4];
        float box_loss = d1 * d1 + d2 * d2 + d3 * d3 + d4 * d4;
        float dpc = b0 - t0;
        float pc_loss = dpc * dpc;

        float cl = 0.0f;
        #pragma unroll
        for (int j = 0; j < 20; ++j) {
            float d = p[10 + j] - t[5 + j];
            cl += d * d;
        }

        float obj_term = LAMBDA_COORD * box_loss + pc_loss + cl;
        float noobj_term = LAMBDA_NOOBJ * (p0 * p0 + p5 * p5);
        loss += (t0 == 1.0f) ? obj_term : noobj_term;

        // all ds_reads done before next iteration overwrites the slice
        asm volatile("s_waitcnt lgkmcnt(0)" ::: "memory");
    }

    // ---- final reduction (once) ----
    #pragma unroll
    for (int off = 32; off > 0; off >>= 1)
        loss += __shfl_down(loss, off, 64);
    if (lane == 0) s_part[wv] = loss;
    __syncthreads();
    if (tid == 0) {
        float s = s_part[0] + s_part[1] + s_part[2] + s_part[3];
        atomicAdd(out, s);
    }
}

extern "C" void kernel_launch(void* const* d_in, const int* in_sizes, int n_in,
                              void* d_out, int out_size, void* d_ws, size_t ws_size,
                              hipStream_t stream) {
    const float* preds   = (const float*)d_in[0];
    const float* targets = (const float*)d_in[1];
    float* out = (float*)d_out;

    const int n_cells = in_sizes[0] / 30;   // 802816 = 12544 * 64

    // d_out is poisoned (0xAA) before every timed replay — zero it on-stream.
    zero_out_kernel<<<(out_size + 255) / 256, 256, 0, stream>>>(out, out_size);

    // 512 blocks = 2 blocks/CU (LDS-bound residency), grid-stride over tiles.
    yolo_loss_kernel<<<512, 256, 0, stream>>>(preds, targets, out, n_cells);
}